// Round 12
// baseline (59.760 us; speedup 1.0000x reference)
//
#include <hip/hip_runtime.h>

#define E  1024
#define H  64
#define BB 8
#define TT 2048

typedef __attribute__((ext_vector_type(8)))  short bf16x8;
typedef __attribute__((ext_vector_type(4)))  float f32x4;
typedef __attribute__((ext_vector_type(16))) float f32x16;
typedef __attribute__((ext_vector_type(8)))  short short8;
typedef __attribute__((ext_vector_type(4)))  short short4v;
typedef __attribute__((ext_vector_type(4)))  unsigned u32x4;

__device__ __forceinline__ short f2bf(float f) {
    union { float f; unsigned u; } v; v.f = f;
    unsigned r = v.u + 0x7FFFu + ((v.u >> 16) & 1u);   // RNE
    return (short)(r >> 16);
}

// fast 2^x via the HW transcendental (no HIP __exp2f intrinsic exists)
__device__ __forceinline__ float fexp2(float x) {
    float r;
    asm("v_exp_f32 %0, %1" : "=v"(r) : "v"(x));
    return r;
}

// 8 fp32 -> bf16x8 via 4x v_cvt_pk_bf16_f32
__device__ __forceinline__ bf16x8 cvt8(float4 a0, float4 a1) {
    unsigned w0, w1, w2, w3;
    asm("v_cvt_pk_bf16_f32 %0, %1, %2" : "=v"(w0) : "v"(a0.x), "v"(a0.y));
    asm("v_cvt_pk_bf16_f32 %0, %1, %2" : "=v"(w1) : "v"(a0.z), "v"(a0.w));
    asm("v_cvt_pk_bf16_f32 %0, %1, %2" : "=v"(w2) : "v"(a1.x), "v"(a1.y));
    asm("v_cvt_pk_bf16_f32 %0, %1, %2" : "=v"(w3) : "v"(a1.z), "v"(a1.w));
    u32x4 u = {w0, w1, w2, w3};
    bf16x8 r;
    __builtin_memcpy(&r, &u, 16);
    return r;
}

// ---- pack W into B-fragment layout for mfma_f32_16x16x32_bf16 ----
__global__ __launch_bounds__(256)
void pack_w(const float* __restrict__ Wq, const float* __restrict__ Wk,
            const float* __restrict__ Wv, short* __restrict__ Wb)
{
    const int t  = blockIdx.x * 256 + threadIdx.x;   // 24576 total
    const int l  = t & 63;
    const int f  = (t >> 6) % 12;
    const int kc = t / 768;                          // kchunk 0..31
    const float* W = (f < 4) ? Wq : ((f < 8) ? Wk : Wv);
    const int e0 = kc * 32 + ((l >> 4) << 3);
    const int n  = ((f & 3) << 4) + (l & 15);
    short8 o;
    #pragma unroll
    for (int j = 0; j < 8; ++j) o[j] = f2bf(W[(e0 + j) * 64 + n]);
    *(short8*)&Wb[(size_t)t * 8] = o;
}

// ---- proj v4: async global_load_lds staging (fp32, source-swizzled) ----
// grid 1024 x 256 thr (4 waves). Block = 16 rows of x staged fp32 in LDS
// via 16 fire-and-forget global_load_lds (width 16); 2 blocks/CU ping-pong
// staging vs compute. Source-address swizzle (16B unit: c ^= r&7) keeps
// ds_read_b128 conflict-free (rule #21: LDS dest stays linear). K-loop x
// reads hit lgkmcnt (decoupled from Wb's vmcnt -> no FIFO cross-drain).
// Wave fg owns 3 output frags over full K: 2 LDS reads + cvt8 + 3 Wb L2
// loads + 3 MFMA per kc; no split-K, no merge.
__global__ __launch_bounds__(256)
void proj_v4(const float* __restrict__ x, const short* __restrict__ Wb,
             short* __restrict__ q, short* __restrict__ k, short* __restrict__ vt)
{
    __shared__ float xs[16 * 1024];      // 64 KB fp32, swizzled 16B units
    const int t = threadIdx.x;
    const long row0 = (long)blockIdx.x * 16;

    // ---- async stage: LDS unit u <- global unit (r = u>>8, c = (u&255)^(r&7))
    #pragma unroll
    for (int i = 0; i < 16; ++i) {
        const int u = i * 256 + t;
        const int r = u >> 8;
        const int c = (u & 255) ^ (r & 7);
        const float* gp = x + (row0 + r) * E + c * 4;
        __builtin_amdgcn_global_load_lds(
            (const __attribute__((address_space(1))) void*)gp,
            (__attribute__((address_space(3))) void*)&xs[u * 4],
            16, 0, 0);
    }
    __syncthreads();   // drains vmcnt before any wave reads LDS

    // ---- compute: wave fg (0..3) -> frags fg*3..fg*3+2, rows 0..15 ----
    const int l   = t & 63;
    const int fg  = t >> 6;
    const int l15 = l & 15, g = l >> 4;
    const int rbase = l15 * 256;         // 16B-unit base of row l15
    const int rswz  = l15 & 7;

    f32x4 acc[3] = {(f32x4){0,0,0,0}, (f32x4){0,0,0,0}, (f32x4){0,0,0,0}};
    const short* wb = Wb + ((size_t)(fg * 3) * 64 + l) * 8;

    #pragma unroll 4
    for (int kc = 0; kc < 32; ++kc) {
        const int c0 = kc * 8 + g * 2;
        float4 xa = *(const float4*)&xs[(rbase + (c0 ^ rswz)) * 4];
        float4 xb = *(const float4*)&xs[(rbase + ((c0 + 1) ^ rswz)) * 4];
        bf16x8 af = cvt8(xa, xb);
        const short* wp = wb + (size_t)kc * 12 * 512;
        bf16x8 b0 = *(const bf16x8*)(wp);
        bf16x8 b1 = *(const bf16x8*)(wp + 512);
        bf16x8 b2 = *(const bf16x8*)(wp + 1024);
        acc[0] = __builtin_amdgcn_mfma_f32_16x16x32_bf16(af, b0, acc[0], 0, 0, 0);
        acc[1] = __builtin_amdgcn_mfma_f32_16x16x32_bf16(af, b1, acc[1], 0, 0, 0);
        acc[2] = __builtin_amdgcn_mfma_f32_16x16x32_bf16(af, b2, acc[2], 0, 0, 0);
    }

    // ---- store: C frag (col=l15, row=g*4+r) ----
    #pragma unroll
    for (int fi = 0; fi < 3; ++fi) {
        const int f = fg * 3 + fi;
        const int m = f >> 2;
        const int h = ((f & 3) << 4) + l15;
        if (m == 2) {
            // Vt[b][h][t], 4 consecutive t in one 8B store
            const long row = row0 + g * 4;
            const long bb = row >> 11;
            const int  t0 = (int)(row & 2047);
            short4v pkt;
            #pragma unroll
            for (int r = 0; r < 4; ++r) pkt[r] = f2bf(acc[fi][r]);
            *(short4v*)&vt[(bb * 64 + h) * TT + t0] = pkt;
        } else {
            short* base = (m == 0) ? q : k;
            // fold 1/sqrt(H) AND log2(e) into q -> softmax uses exp2
            const float sc = (m == 0) ? (0.125f * 1.44269504f) : 1.0f;
            #pragma unroll
            for (int r = 0; r < 4; ++r)
                base[(row0 + g * 4 + r) * 64 + h] = f2bf(acc[fi][r] * sc);
        }
    }
}

// ---- 32x32 swapped-QK^T flash attention (T12: cvt_pk + permlane32_swap) ----
// Grid 256 = 32 tile-pairs x 8 batches (b = bid&7 -> XCD pin). Block = 512
// thr = 8 waves on tile pair (pr, 63-pr) = 65 chunks of 32 kv; waves split
// proportionally (8-10 chunks each). Swapped QK^T: lane owns q-row (L&31),
// P^T col in regs -> lane-local softmax, in-register P->bf16 B-frags.
__global__ __launch_bounds__(512)
void attn_v8(const short* __restrict__ qg,
             const short* __restrict__ kg,
             const short* __restrict__ vtg,
             float* __restrict__ out)
{
    __shared__ float Op[8][32][66];      // per-wave O^T partials [w][q][h]
    __shared__ float Ml[8][32][2];       // per-wave (m, l)

    const int t   = threadIdx.x;
    const int L   = t & 63;
    const int w   = t >> 6;
    const int bid = blockIdx.x;
    const int b   = bid & 7;             // XCD pin
    const int pr  = bid >> 3;            // pair 0..31
    const int l31 = L & 31, hi = L >> 5;

    const int stA = pr, stB = 63 - pr;
    const int nA = stA + 1;
    int WA = (8 * nA + 32) / 65;         // round(8*nA/65)
    WA = WA < 1 ? 1 : (WA > 7 ? 7 : WA);
    const int WB = 8 - WA;

    const bool isB  = (w >= WA);
    const int  st   = isB ? stB : stA;
    const int  q0   = st * 32;
    const int  strd = isB ? WB : WA;
    const int  c0   = isB ? (w - WA) : w;

    // Q B-frags: col=q=l31, k=e=es*16+hi*8+j
    bf16x8 qf[4];
    {
        const short* qp = qg + ((long)b * TT + q0 + l31) * 64 + hi * 8;
        qf[0] = *(const bf16x8*)(qp);
        qf[1] = *(const bf16x8*)(qp + 16);
        qf[2] = *(const bf16x8*)(qp + 32);
        qf[3] = *(const bf16x8*)(qp + 48);
    }

    f32x16 o0 = {}, o1 = {};
    float mrun = -1e30f, lrun = 0.f;

    const short* kbase = kg  + ((long)b * TT + l31) * 64 + hi * 8;
    const short* vbase = vtg + ((long)b * 64 + l31) * TT + hi * 8;

    for (int ci = c0; ci <= st; ci += strd) {
        const int kvs = ci * 32;
        // K A-frags: row=kv=kvs+l31, k=e (contiguous 16B)
        const short* kp = kbase + (long)kvs * 64;
        bf16x8 kf0 = *(const bf16x8*)(kp);
        bf16x8 kf1 = *(const bf16x8*)(kp + 16);
        bf16x8 kf2 = *(const bf16x8*)(kp + 32);
        bf16x8 kf3 = *(const bf16x8*)(kp + 48);
        // V A-frags issued early: row=h=nf*32+l31, k=kv slice
        const short* vp = vbase + kvs;
        bf16x8 vf00 = *(const bf16x8*)(vp);
        bf16x8 vf01 = *(const bf16x8*)(vp + 16);
        bf16x8 vf10 = *(const bf16x8*)(vp + 32 * TT);
        bf16x8 vf11 = *(const bf16x8*)(vp + 32 * TT + 16);

        // ---- QK^T swapped: S^T[kv,q]; D: col=q=l31, row=crow(r,hi) ----
        f32x16 s = {};
        __builtin_amdgcn_s_setprio(1);
        s = __builtin_amdgcn_mfma_f32_32x32x16_bf16(kf0, qf[0], s, 0, 0, 0);
        s = __builtin_amdgcn_mfma_f32_32x32x16_bf16(kf1, qf[1], s, 0, 0, 0);
        s = __builtin_amdgcn_mfma_f32_32x32x16_bf16(kf2, qf[2], s, 0, 0, 0);
        s = __builtin_amdgcn_mfma_f32_32x32x16_bf16(kf3, qf[3], s, 0, 0, 0);
        __builtin_amdgcn_s_setprio(0);

        // ---- causal mask: only the diagonal chunk ----
        if (kvs == q0) {
            #pragma unroll
            for (int r = 0; r < 16; ++r) {
                const int crow = (r & 3) + 8 * (r >> 2) + 4 * hi;
                if (crow > l31) s[r] = -1e30f;
            }
        }
        // ---- lane-local row max (q-row = l31) + hi-half exchange ----
        float m01 = fmaxf(s[0], s[1]),   m23 = fmaxf(s[2], s[3]);
        float m45 = fmaxf(s[4], s[5]),   m67 = fmaxf(s[6], s[7]);
        float m89 = fmaxf(s[8], s[9]),   mab = fmaxf(s[10], s[11]);
        float mcd = fmaxf(s[12], s[13]), mef = fmaxf(s[14], s[15]);
        float mloc = fmaxf(fmaxf(fmaxf(m01, m23), fmaxf(m45, m67)),
                           fmaxf(fmaxf(m89, mab), fmaxf(mcd, mef)));
        mloc = fmaxf(mloc, __shfl_xor(mloc, 32));
        // ---- defer-max rescale (THR = 8 in exp2 units) ----
        if (__any(mloc > mrun + 8.f)) {
            const float mnew = fmaxf(mrun, mloc);
            const float a = fexp2(mrun - mnew);
            mrun = mnew;
            lrun *= a;
            #pragma unroll
            for (int r = 0; r < 16; ++r) { o0[r] *= a; o1[r] *= a; }
        }
        // ---- p = exp2(s - m) in place; lane-local sum ----
        #pragma unroll
        for (int r = 0; r < 16; ++r) s[r] = fexp2(s[r] - mrun);
        {
            float s01 = (s[0] + s[1]) + (s[2] + s[3]);
            float s23 = (s[4] + s[5]) + (s[6] + s[7]);
            float s45 = (s[8] + s[9]) + (s[10] + s[11]);
            float s67 = (s[12] + s[13]) + (s[14] + s[15]);
            float lsum = (s01 + s23) + (s45 + s67);
            lsum += __shfl_xor(lsum, 32);
            lrun += lsum;
        }
        // ---- in-register P->bf16 B-frags: 8 cvt_pk + 4 permlane32_swap ----
        unsigned wv[8];
        #pragma unroll
        for (int i = 0; i < 8; ++i)
            asm("v_cvt_pk_bf16_f32 %0, %1, %2" : "=v"(wv[i]) : "v"(s[2 * i]), "v"(s[2 * i + 1]));
        unsigned p00 = wv[0], p02 = wv[2];   // ks=0: words 0,2
        unsigned p01 = wv[1], p03 = wv[3];   // ks=0: words 1,3
        unsigned p10 = wv[4], p12 = wv[6];   // ks=1
        unsigned p11 = wv[5], p13 = wv[7];
        asm("v_permlane32_swap_b32 %0, %1" : "+v"(p00), "+v"(p02));
        asm("v_permlane32_swap_b32 %0, %1" : "+v"(p01), "+v"(p03));
        asm("v_permlane32_swap_b32 %0, %1" : "+v"(p10), "+v"(p12));
        asm("v_permlane32_swap_b32 %0, %1" : "+v"(p11), "+v"(p13));
        u32x4 pb0u = {p00, p01, p02, p03};
        u32x4 pb1u = {p10, p11, p12, p13};
        bf16x8 pb0, pb1;
        __builtin_memcpy(&pb0, &pb0u, 16);
        __builtin_memcpy(&pb1, &pb1u, 16);
        // ---- PV: O^T[h,q] += V^T x P^T ----
        __builtin_amdgcn_s_setprio(1);
        o0 = __builtin_amdgcn_mfma_f32_32x32x16_bf16(vf00, pb0, o0, 0, 0, 0);
        o0 = __builtin_amdgcn_mfma_f32_32x32x16_bf16(vf01, pb1, o0, 0, 0, 0);
        o1 = __builtin_amdgcn_mfma_f32_32x32x16_bf16(vf10, pb0, o1, 0, 0, 0);
        o1 = __builtin_amdgcn_mfma_f32_32x32x16_bf16(vf11, pb1, o1, 0, 0, 0);
        __builtin_amdgcn_s_setprio(0);
    }

    // ---- publish partials; single barrier; variable-width merge ----
    #pragma unroll
    for (int r = 0; r < 16; ++r) {
        const int h = (r & 3) + 8 * (r >> 2) + 4 * hi;
        Op[w][l31][h]      = o0[r];
        Op[w][l31][32 + h] = o1[r];
    }
    if (hi == 0) {
        Ml[w][l31][0] = mrun;
        Ml[w][l31][1] = lrun;
    }
    __syncthreads();

    // waves 0-3 merge tile A rows, 4-7 tile B rows; lane L = output col h
    {
        const bool tb   = (w >= 4);
        const int  base = tb ? WA : 0;
        const int  cnt  = tb ? WB : WA;
        const long oq0  = (long)(tb ? stB : stA) * 32;
        #pragma unroll
        for (int rr = 0; rr < 8; ++rr) {
            const int row = (w & 3) * 8 + rr;
            float M = -1e30f;
            for (int j = 0; j < cnt; ++j)
                M = fmaxf(M, Ml[base + j][row][0]);
            float Ls = 0.f, val = 0.f;
            for (int j = 0; j < cnt; ++j) {
                const float a = fexp2(Ml[base + j][row][0] - M);
                Ls  += a * Ml[base + j][row][1];
                val += a * Op[base + j][row][L];
            }
            out[((long)b * TT + oq0 + row) * 64 + L] = val / Ls;
        }
    }
}

extern "C" void kernel_launch(void* const* d_in, const int* in_sizes, int n_in,
                              void* d_out, int out_size, void* d_ws, size_t ws_size,
                              hipStream_t stream)
{
    const float* x  = (const float*)d_in[0];
    const float* Wq = (const float*)d_in[1];
    const float* Wk = (const float*)d_in[2];
    const float* Wv = (const float*)d_in[3];
    float* out = (float*)d_out;

    const size_t n = (size_t)BB * TT * H;   // 1,048,576 per tensor
    short* q  = (short*)d_ws;
    short* k  = q + n;
    short* vt = k + n;                      // V transposed: [B][H][T]
    short* Wb = vt + n;                     // 196,608 shorts

    pack_w  <<<dim3(96),   256, 0, stream>>>(Wq, Wk, Wv, Wb);
    proj_v4 <<<dim3(1024), 256, 0, stream>>>(x, Wb, q, k, vt);
    attn_v8 <<<dim3(256),  512, 0, stream>>>(q, k, vt, out);
}

// Round 13
// 58.853 us; speedup vs baseline: 1.0154x; 1.0154x over previous
//
#include <hip/hip_runtime.h>

#define E  1024
#define H  64
#define BB 8
#define TT 2048

typedef __attribute__((ext_vector_type(8)))  short bf16x8;
typedef __attribute__((ext_vector_type(4)))  float f32x4;
typedef __attribute__((ext_vector_type(16))) float f32x16;
typedef __attribute__((ext_vector_type(8)))  short short8;
typedef __attribute__((ext_vector_type(4)))  short short4v;
typedef __attribute__((ext_vector_type(4)))  unsigned u32x4;

__device__ __forceinline__ short f2bf(float f) {
    union { float f; unsigned u; } v; v.f = f;
    unsigned r = v.u + 0x7FFFu + ((v.u >> 16) & 1u);   // RNE
    return (short)(r >> 16);
}

// fast 2^x via the HW transcendental (no HIP __exp2f intrinsic exists)
__device__ __forceinline__ float fexp2(float x) {
    float r;
    asm("v_exp_f32 %0, %1" : "=v"(r) : "v"(x));
    return r;
}

// 8 fp32 -> bf16x8 via 4x v_cvt_pk_bf16_f32
__device__ __forceinline__ bf16x8 cvt8(float4 a0, float4 a1) {
    unsigned w0, w1, w2, w3;
    asm("v_cvt_pk_bf16_f32 %0, %1, %2" : "=v"(w0) : "v"(a0.x), "v"(a0.y));
    asm("v_cvt_pk_bf16_f32 %0, %1, %2" : "=v"(w1) : "v"(a0.z), "v"(a0.w));
    asm("v_cvt_pk_bf16_f32 %0, %1, %2" : "=v"(w2) : "v"(a1.x), "v"(a1.y));
    asm("v_cvt_pk_bf16_f32 %0, %1, %2" : "=v"(w3) : "v"(a1.z), "v"(a1.w));
    u32x4 u = {w0, w1, w2, w3};
    bf16x8 r;
    __builtin_memcpy(&r, &u, 16);
    return r;
}

// ---- pack W into B-fragment layout for mfma_f32_16x16x32_bf16 ----
__global__ __launch_bounds__(256)
void pack_w(const float* __restrict__ Wq, const float* __restrict__ Wk,
            const float* __restrict__ Wv, short* __restrict__ Wb)
{
    const int t  = blockIdx.x * 256 + threadIdx.x;   // 24576 total
    const int l  = t & 63;
    const int f  = (t >> 6) % 12;
    const int kc = t / 768;                          // kchunk 0..31
    const float* W = (f < 4) ? Wq : ((f < 8) ? Wk : Wv);
    const int e0 = kc * 32 + ((l >> 4) << 3);
    const int n  = ((f & 3) << 4) + (l & 15);
    short8 o;
    #pragma unroll
    for (int j = 0; j < 8; ++j) o[j] = f2bf(W[(e0 + j) * 64 + n]);
    *(short8*)&Wb[(size_t)t * 8] = o;
}

// ---- proj v5: 64 rows/block, B amortized over 4 row-tiles ----
// grid 256 x 256 thr (1 block/CU). x staged bf16 in 128 KB LDS (16B-unit
// XOR swizzle c^=(r&7) -> conflict-free ds_read_b128). Wave fg owns 3
// output frags x 64 rows: per kc, 3 Wb loads (L2) are consumed by 12
// MFMAs over 4 A-frags -> Wb L2 traffic /4 (402->100 MB) and 4x the
// MFMA work per L2 dependency.
__global__ __launch_bounds__(256)
void proj_v5(const float* __restrict__ x, const short* __restrict__ Wb,
             short* __restrict__ q, short* __restrict__ k, short* __restrict__ vt)
{
    __shared__ short xs[64 * 1024];      // 128 KB bf16
    const int t = threadIdx.x;
    const long row0 = (long)blockIdx.x * 64;

    // ---- stage: 8192 16B-units; 32/thread in 4 batches of 8 (16 loads in flight)
    #pragma unroll
    for (int b8 = 0; b8 < 4; ++b8) {
        float4 va[16];
        #pragma unroll
        for (int j = 0; j < 8; ++j) {
            const int u = (b8 * 8 + j) * 256 + t;
            const int r = u >> 7, c = u & 127;
            const float* p = x + (row0 + r) * E + c * 8;
            va[j * 2]     = *(const float4*)(p);
            va[j * 2 + 1] = *(const float4*)(p + 4);
        }
        #pragma unroll
        for (int j = 0; j < 8; ++j) {
            const int u = (b8 * 8 + j) * 256 + t;
            const int r = u >> 7, c = u & 127;
            *(bf16x8*)&xs[(r * 128 + (c ^ (r & 7))) * 8] = cvt8(va[j * 2], va[j * 2 + 1]);
        }
    }
    __syncthreads();

    // ---- compute: wave fg (0..3) -> frags fg*3..+2, row-tiles rt 0..3 ----
    const int l   = t & 63;
    const int fg  = t >> 6;
    const int l15 = l & 15, g = l >> 4;
    const int swz = l15 & 7;

    f32x4 acc[4][3] = {};
    const short* wb = Wb + ((size_t)(fg * 3) * 64 + l) * 8;

    #pragma unroll 4
    for (int kc = 0; kc < 32; ++kc) {
        const short* wp = wb + (size_t)kc * 12 * 512;
        bf16x8 b0 = *(const bf16x8*)(wp);
        bf16x8 b1 = *(const bf16x8*)(wp + 512);
        bf16x8 b2 = *(const bf16x8*)(wp + 1024);
        const int cu = (kc * 4 + g) ^ swz;
        #pragma unroll
        for (int rt = 0; rt < 4; ++rt) {
            bf16x8 af = *(const bf16x8*)&xs[((rt * 16 + l15) * 128 + cu) * 8];
            acc[rt][0] = __builtin_amdgcn_mfma_f32_16x16x32_bf16(af, b0, acc[rt][0], 0, 0, 0);
            acc[rt][1] = __builtin_amdgcn_mfma_f32_16x16x32_bf16(af, b1, acc[rt][1], 0, 0, 0);
            acc[rt][2] = __builtin_amdgcn_mfma_f32_16x16x32_bf16(af, b2, acc[rt][2], 0, 0, 0);
        }
    }

    // ---- store: C frag (col=l15, row=g*4+r) per row-tile ----
    #pragma unroll
    for (int rt = 0; rt < 4; ++rt) {
        const long rowb = row0 + rt * 16;
        #pragma unroll
        for (int fi = 0; fi < 3; ++fi) {
            const int f = fg * 3 + fi;
            const int m = f >> 2;
            const int h = ((f & 3) << 4) + l15;
            if (m == 2) {
                // Vt[b][h][t], 4 consecutive t in one 8B store
                const long row = rowb + g * 4;
                const long bb = row >> 11;
                const int  t0 = (int)(row & 2047);
                short4v pkt;
                #pragma unroll
                for (int r = 0; r < 4; ++r) pkt[r] = f2bf(acc[rt][fi][r]);
                *(short4v*)&vt[(bb * 64 + h) * TT + t0] = pkt;
            } else {
                short* base = (m == 0) ? q : k;
                // fold 1/sqrt(H) AND log2(e) into q -> softmax uses exp2
                const float sc = (m == 0) ? (0.125f * 1.44269504f) : 1.0f;
                #pragma unroll
                for (int r = 0; r < 4; ++r)
                    base[(rowb + g * 4 + r) * 64 + h] = f2bf(acc[rt][fi][r] * sc);
            }
        }
    }
}

// ---- 32x32 swapped-QK^T flash attention (T12: cvt_pk + permlane32_swap) ----
// Grid 256 = 32 tile-pairs x 8 batches (b = bid&7 -> XCD pin). Block = 512
// thr = 8 waves on tile pair (pr, 63-pr) = 65 chunks of 32 kv; waves split
// proportionally (8-10 chunks each). Swapped QK^T: lane owns q-row (L&31),
// P^T col in regs -> lane-local softmax, in-register P->bf16 B-frags.
__global__ __launch_bounds__(512)
void attn_v8(const short* __restrict__ qg,
             const short* __restrict__ kg,
             const short* __restrict__ vtg,
             float* __restrict__ out)
{
    __shared__ float Op[8][32][66];      // per-wave O^T partials [w][q][h]
    __shared__ float Ml[8][32][2];       // per-wave (m, l)

    const int t   = threadIdx.x;
    const int L   = t & 63;
    const int w   = t >> 6;
    const int bid = blockIdx.x;
    const int b   = bid & 7;             // XCD pin
    const int pr  = bid >> 3;            // pair 0..31
    const int l31 = L & 31, hi = L >> 5;

    const int stA = pr, stB = 63 - pr;
    const int nA = stA + 1;
    int WA = (8 * nA + 32) / 65;         // round(8*nA/65)
    WA = WA < 1 ? 1 : (WA > 7 ? 7 : WA);
    const int WB = 8 - WA;

    const bool isB  = (w >= WA);
    const int  st   = isB ? stB : stA;
    const int  q0   = st * 32;
    const int  strd = isB ? WB : WA;
    const int  c0   = isB ? (w - WA) : w;

    // Q B-frags: col=q=l31, k=e=es*16+hi*8+j
    bf16x8 qf[4];
    {
        const short* qp = qg + ((long)b * TT + q0 + l31) * 64 + hi * 8;
        qf[0] = *(const bf16x8*)(qp);
        qf[1] = *(const bf16x8*)(qp + 16);
        qf[2] = *(const bf16x8*)(qp + 32);
        qf[3] = *(const bf16x8*)(qp + 48);
    }

    f32x16 o0 = {}, o1 = {};
    float mrun = -1e30f, lrun = 0.f;

    const short* kbase = kg  + ((long)b * TT + l31) * 64 + hi * 8;
    const short* vbase = vtg + ((long)b * 64 + l31) * TT + hi * 8;

    for (int ci = c0; ci <= st; ci += strd) {
        const int kvs = ci * 32;
        // K A-frags: row=kv=kvs+l31, k=e (contiguous 16B)
        const short* kp = kbase + (long)kvs * 64;
        bf16x8 kf0 = *(const bf16x8*)(kp);
        bf16x8 kf1 = *(const bf16x8*)(kp + 16);
        bf16x8 kf2 = *(const bf16x8*)(kp + 32);
        bf16x8 kf3 = *(const bf16x8*)(kp + 48);
        // V A-frags issued early: row=h=nf*32+l31, k=kv slice
        const short* vp = vbase + kvs;
        bf16x8 vf00 = *(const bf16x8*)(vp);
        bf16x8 vf01 = *(const bf16x8*)(vp + 16);
        bf16x8 vf10 = *(const bf16x8*)(vp + 32 * TT);
        bf16x8 vf11 = *(const bf16x8*)(vp + 32 * TT + 16);

        // ---- QK^T swapped: S^T[kv,q]; D: col=q=l31, row=crow(r,hi) ----
        f32x16 s = {};
        __builtin_amdgcn_s_setprio(1);
        s = __builtin_amdgcn_mfma_f32_32x32x16_bf16(kf0, qf[0], s, 0, 0, 0);
        s = __builtin_amdgcn_mfma_f32_32x32x16_bf16(kf1, qf[1], s, 0, 0, 0);
        s = __builtin_amdgcn_mfma_f32_32x32x16_bf16(kf2, qf[2], s, 0, 0, 0);
        s = __builtin_amdgcn_mfma_f32_32x32x16_bf16(kf3, qf[3], s, 0, 0, 0);
        __builtin_amdgcn_s_setprio(0);

        // ---- causal mask: only the diagonal chunk ----
        if (kvs == q0) {
            #pragma unroll
            for (int r = 0; r < 16; ++r) {
                const int crow = (r & 3) + 8 * (r >> 2) + 4 * hi;
                if (crow > l31) s[r] = -1e30f;
            }
        }
        // ---- lane-local row max (q-row = l31) + hi-half exchange ----
        float m01 = fmaxf(s[0], s[1]),   m23 = fmaxf(s[2], s[3]);
        float m45 = fmaxf(s[4], s[5]),   m67 = fmaxf(s[6], s[7]);
        float m89 = fmaxf(s[8], s[9]),   mab = fmaxf(s[10], s[11]);
        float mcd = fmaxf(s[12], s[13]), mef = fmaxf(s[14], s[15]);
        float mloc = fmaxf(fmaxf(fmaxf(m01, m23), fmaxf(m45, m67)),
                           fmaxf(fmaxf(m89, mab), fmaxf(mcd, mef)));
        mloc = fmaxf(mloc, __shfl_xor(mloc, 32));
        // ---- defer-max rescale (THR = 8 in exp2 units) ----
        if (__any(mloc > mrun + 8.f)) {
            const float mnew = fmaxf(mrun, mloc);
            const float a = fexp2(mrun - mnew);
            mrun = mnew;
            lrun *= a;
            #pragma unroll
            for (int r = 0; r < 16; ++r) { o0[r] *= a; o1[r] *= a; }
        }
        // ---- p = exp2(s - m) in place; lane-local sum ----
        #pragma unroll
        for (int r = 0; r < 16; ++r) s[r] = fexp2(s[r] - mrun);
        {
            float s01 = (s[0] + s[1]) + (s[2] + s[3]);
            float s23 = (s[4] + s[5]) + (s[6] + s[7]);
            float s45 = (s[8] + s[9]) + (s[10] + s[11]);
            float s67 = (s[12] + s[13]) + (s[14] + s[15]);
            float lsum = (s01 + s23) + (s45 + s67);
            lsum += __shfl_xor(lsum, 32);
            lrun += lsum;
        }
        // ---- in-register P->bf16 B-frags: 8 cvt_pk + 4 permlane32_swap ----
        unsigned wv[8];
        #pragma unroll
        for (int i = 0; i < 8; ++i)
            asm("v_cvt_pk_bf16_f32 %0, %1, %2" : "=v"(wv[i]) : "v"(s[2 * i]), "v"(s[2 * i + 1]));
        unsigned p00 = wv[0], p02 = wv[2];   // ks=0: words 0,2
        unsigned p01 = wv[1], p03 = wv[3];   // ks=0: words 1,3
        unsigned p10 = wv[4], p12 = wv[6];   // ks=1
        unsigned p11 = wv[5], p13 = wv[7];
        asm("v_permlane32_swap_b32 %0, %1" : "+v"(p00), "+v"(p02));
        asm("v_permlane32_swap_b32 %0, %1" : "+v"(p01), "+v"(p03));
        asm("v_permlane32_swap_b32 %0, %1" : "+v"(p10), "+v"(p12));
        asm("v_permlane32_swap_b32 %0, %1" : "+v"(p11), "+v"(p13));
        u32x4 pb0u = {p00, p01, p02, p03};
        u32x4 pb1u = {p10, p11, p12, p13};
        bf16x8 pb0, pb1;
        __builtin_memcpy(&pb0, &pb0u, 16);
        __builtin_memcpy(&pb1, &pb1u, 16);
        // ---- PV: O^T[h,q] += V^T x P^T ----
        __builtin_amdgcn_s_setprio(1);
        o0 = __builtin_amdgcn_mfma_f32_32x32x16_bf16(vf00, pb0, o0, 0, 0, 0);
        o0 = __builtin_amdgcn_mfma_f32_32x32x16_bf16(vf01, pb1, o0, 0, 0, 0);
        o1 = __builtin_amdgcn_mfma_f32_32x32x16_bf16(vf10, pb0, o1, 0, 0, 0);
        o1 = __builtin_amdgcn_mfma_f32_32x32x16_bf16(vf11, pb1, o1, 0, 0, 0);
        __builtin_amdgcn_s_setprio(0);
    }

    // ---- publish partials; single barrier; variable-width merge ----
    #pragma unroll
    for (int r = 0; r < 16; ++r) {
        const int h = (r & 3) + 8 * (r >> 2) + 4 * hi;
        Op[w][l31][h]      = o0[r];
        Op[w][l31][32 + h] = o1[r];
    }
    if (hi == 0) {
        Ml[w][l31][0] = mrun;
        Ml[w][l31][1] = lrun;
    }
    __syncthreads();

    // waves 0-3 merge tile A rows, 4-7 tile B rows; lane L = output col h
    {
        const bool tb   = (w >= 4);
        const int  base = tb ? WA : 0;
        const int  cnt  = tb ? WB : WA;
        const long oq0  = (long)(tb ? stB : stA) * 32;
        #pragma unroll
        for (int rr = 0; rr < 8; ++rr) {
            const int row = (w & 3) * 8 + rr;
            float M = -1e30f;
            for (int j = 0; j < cnt; ++j)
                M = fmaxf(M, Ml[base + j][row][0]);
            float Ls = 0.f, val = 0.f;
            for (int j = 0; j < cnt; ++j) {
                const float a = fexp2(Ml[base + j][row][0] - M);
                Ls  += a * Ml[base + j][row][1];
                val += a * Op[base + j][row][L];
            }
            out[((long)b * TT + oq0 + row) * 64 + L] = val / Ls;
        }
    }
}

extern "C" void kernel_launch(void* const* d_in, const int* in_sizes, int n_in,
                              void* d_out, int out_size, void* d_ws, size_t ws_size,
                              hipStream_t stream)
{
    const float* x  = (const float*)d_in[0];
    const float* Wq = (const float*)d_in[1];
    const float* Wk = (const float*)d_in[2];
    const float* Wv = (const float*)d_in[3];
    float* out = (float*)d_out;

    const size_t n = (size_t)BB * TT * H;   // 1,048,576 per tensor
    short* q  = (short*)d_ws;
    short* k  = q + n;
    short* vt = k + n;                      // V transposed: [B][H][T]
    short* Wb = vt + n;                     // 196,608 shorts

    pack_w  <<<dim3(96),  256, 0, stream>>>(Wq, Wk, Wv, Wb);
    proj_v5 <<<dim3(256), 256, 0, stream>>>(x, Wb, q, k, vt);
    attn_v8 <<<dim3(256), 512, 0, stream>>>(q, k, vt, out);
}